// Round 1
// baseline (71.040 us; speedup 1.0000x reference)
//
#include <hip/hip_runtime.h>
#include <stdint.h>

#define NROWS 8192
#define FDIM  256
#define DDIM  64

constexpr int RPB = 64;    // rows per block (lane = row within wave)
constexpr int CPB = 32;    // cols per block (2 blocks in y cover D=64)
constexpr int XS  = 258;   // bf16 words per LDS row (256 + 2 pad; 258%32=2 -> (lane + f/2)%32 banks, 2-way = free)

// Pack two fp32 -> bf16x2 with round-to-nearest-even (inputs are finite; no NaN path needed).
__device__ inline unsigned int pack2_bf16_rne(float a, float b) {
    unsigned int ua = __float_as_uint(a);
    unsigned int ub = __float_as_uint(b);
    ua += 0x7fffu + ((ua >> 16) & 1u);
    ub += 0x7fffu + ((ub >> 16) & 1u);
    return (ua >> 16) | (ub & 0xffff0000u);
}

__global__ __launch_bounds__(256)
void nanembed_kernel(const float* __restrict__ x,
                     const float* __restrict__ W,
                     const float* __restrict__ b,
                     float* __restrict__ out)
{
    // x tile as bf16: 64 rows * 258 words * 2B = 33024 B. Reused as fp32 partial buffer
    // p[w][c][r] = 4*32*64*4B = 32768 B after compute phase.
    __shared__ __align__(16) unsigned short xs[RPB * XS];
    __shared__ float bias_part[8][32];
    __shared__ float bm[32];

    const int tid  = threadIdx.x;
    const int lane = tid & 63;
    const int wave = tid >> 6;
    const int wu   = __builtin_amdgcn_readfirstlane(wave);  // force SGPR -> W loads become s_load
    const int row0 = blockIdx.x * RPB;      // 128 row groups
    const int c0   = blockIdx.y * CPB;      // 2 col halves

    // ---- Stage x tile (fp32 global -> bf16 LDS), coalesced float4 loads ----
    {
        const float4* xv4 = reinterpret_cast<const float4*>(x + (size_t)row0 * FDIM);
        #pragma unroll
        for (int i = 0; i < 16; ++i) {
            int idx = tid + i * 256;        // 0..4095 float4s over the 64x256 tile
            int r   = idx >> 6;             // 64 float4 per row
            int s   = idx & 63;
            float4 v = xv4[idx];
            unsigned int u0 = pack2_bf16_rne(v.x, v.y);
            unsigned int u1 = pack2_bf16_rne(v.z, v.w);
            unsigned int* dst = reinterpret_cast<unsigned int*>(&xs[r * XS + s * 4]);
            dst[0] = u0;
            dst[1] = u1;
        }
    }

    // ---- Bias partial sums: bias_part[fs][c] = sum over 32 f of b[f][c0+c] ----
    {
        const int c  = tid & 31;
        const int fs = tid >> 5;            // 0..7
        float s = 0.f;
        #pragma unroll 8
        for (int k = 0; k < 32; ++k)
            s += b[(size_t)(fs * 32 + k) * DDIM + c0 + c];
        bias_part[fs][c] = s;
    }

    __syncthreads();  // staging + bias_part visible

    // ---- Compute: wave wu handles f in [64*wu, 64*wu+64); lane = row; acc over 32 cols ----
    float acc[CPB];
    #pragma unroll
    for (int c = 0; c < CPB; ++c) acc[c] = 0.f;

    const int fbase = wu * 64;
    const float* __restrict__ Wb = W + (size_t)fbase * DDIM + c0;  // wave-uniform
    const unsigned short* xrow = &xs[lane * XS + fbase];

    #pragma unroll 4
    for (int f2 = 0; f2 < 32; ++f2) {
        // one bf16 pair per ds_read_b32; bank = (lane + f/2)%32 -> 2-way, free
        unsigned int uw = *reinterpret_cast<const unsigned int*>(xrow + 2 * f2);
        float xlo = __uint_as_float(uw << 16);
        float xhi = __uint_as_float(uw & 0xffff0000u);
        const float* w0 = Wb + (size_t)(2 * f2) * DDIM;
        const float* w1 = Wb + (size_t)(2 * f2 + 1) * DDIM;
        #pragma unroll
        for (int c = 0; c < CPB; ++c) acc[c] = fmaf(xlo, w0[c], acc[c]);
        #pragma unroll
        for (int c = 0; c < CPB; ++c) acc[c] = fmaf(xhi, w1[c], acc[c]);
    }

    __syncthreads();  // everyone done reading xs; safe to repurpose as partial buffer

    // ---- Cross-wave reduction via LDS: p[w][c][r], bank = r%32 -> conflict-free ----
    float* pbuf = reinterpret_cast<float*>(xs);
    #pragma unroll
    for (int c = 0; c < CPB; ++c)
        pbuf[(wu * CPB + c) * 64 + lane] = acc[c];

    if (tid < CPB) {
        float s = 0.f;
        #pragma unroll
        for (int k = 0; k < 8; ++k) s += bias_part[k][tid];
        bm[tid] = s;
    }

    __syncthreads();

    // ---- Epilogue: thread -> (row r = tid/4, col block cb = (tid%4)*8); coalesced float4 x2 ----
    {
        const int r  = tid >> 2;
        const int cb = (tid & 3) * 8;
        float4 o[2];
        float* of = reinterpret_cast<float*>(o);
        #pragma unroll
        for (int j = 0; j < 8; ++j) {
            const int c = cb + j;
            float s = bm[c];
            #pragma unroll
            for (int w = 0; w < 4; ++w)
                s += pbuf[(w * CPB + c) * 64 + r];
            of[j] = s * (1.0f / 256.0f);
        }
        float4* op = reinterpret_cast<float4*>(out + (size_t)(row0 + r) * DDIM + c0 + cb);
        op[0] = o[0];
        op[1] = o[1];
    }
}

extern "C" void kernel_launch(void* const* d_in, const int* in_sizes, int n_in,
                              void* d_out, int out_size, void* d_ws, size_t ws_size,
                              hipStream_t stream) {
    const float* x = (const float*)d_in[0];   // [8192, 256]
    const float* W = (const float*)d_in[1];   // [256, 64]
    const float* b = (const float*)d_in[2];   // [256, 64]
    float* out = (float*)d_out;               // [8192, 64]

    dim3 grid(NROWS / RPB, DDIM / CPB);       // (128, 2) = 256 blocks, 1 per CU
    nanembed_kernel<<<grid, 256, 0, stream>>>(x, W, b, out);
}

// Round 2
// 65.557 us; speedup vs baseline: 1.0836x; 1.0836x over previous
//
#include <hip/hip_runtime.h>
#include <stdint.h>

#define NROWS 8192
#define FDIM  256   // K (feature dim)
#define DDIM  64    // N (out dim)

typedef __attribute__((ext_vector_type(8))) short short8;   // 8 bf16 = 4 VGPR (MFMA A/B frag)
typedef __attribute__((ext_vector_type(4))) float floatx4;  // MFMA C/D frag

// Pack two fp32 -> bf16x2, round-to-nearest-even (inputs finite; no NaN path needed).
__device__ inline unsigned int pack2_bf16(float a, float b) {
    unsigned int ua = __float_as_uint(a);
    unsigned int ub = __float_as_uint(b);
    ua += 0x7fffu + ((ua >> 16) & 1u);
    ub += 0x7fffu + ((ub >> 16) & 1u);
    return (ua >> 16) | (ub & 0xffff0000u);
}

// Block: 128 threads = 2 waves; each wave computes 16 rows x 64 cols via
// mfma_f32_16x16x32_bf16 (4 n-tiles x 8 k-steps = 32 MFMAs). Grid: 256 blocks
// (8192/32 rows), 1 block/CU.
//
// Layouts (verified per guide §3):
//   A[m=lane&15][k=(lane>>4)*8+j]   (x rows, straight from global, packed in regs)
//   B[k=(lane>>4)*8+j][n=lane&15]   (W, pre-packed frag-ready in LDS -> 1 ds_read_b128/MFMA)
//   D col=lane&15, row=(lane>>4)*4+reg
__global__ __launch_bounds__(128)
void nanembed_mfma(const float* __restrict__ x,
                   const float* __restrict__ W,
                   const float* __restrict__ b,
                   float* __restrict__ out)
{
    // 2048 B-frags (8 ksteps x 4 ntiles x 64 lanes) x 16B = 32 KB
    __shared__ __align__(16) unsigned int bfrag_lds[2048 * 4];
    __shared__ float4 bias_part[8][16];   // 2 KB: partial colsum(b), 8 f-chunks x 64 cols

    const int tid  = threadIdx.x;     // 0..127
    const int lane = tid & 63;
    const int w    = tid >> 6;        // wave id 0/1
    const int q    = lane >> 4;       // quad 0..3
    const int n    = lane & 15;
    const int r0   = blockIdx.x * 32;

    // ---- 1) x loads first: 16 dwordx4/lane issued before any LDS work so HBM
    //         reads are in flight while we stage W. A-frag needs
    //         x[r0+w*16+n][ks*32 + q*8 + 0..7] -> two float4 per k-step.
    const int row = r0 + w * 16 + n;
    const float4* xp = reinterpret_cast<const float4*>(x + (size_t)row * FDIM + q * 8);
    float4 xv[16];
    #pragma unroll
    for (int ks = 0; ks < 8; ++ks) {
        xv[2 * ks]     = xp[ks * 8];      // floats [ks*32+q*8 .. +3]
        xv[2 * ks + 1] = xp[ks * 8 + 1];  // floats [ks*32+q*8+4 .. +7]
    }

    // ---- 2) Stage W into frag-ready LDS layout: frag f = ks*256 + nt*64 + lane.
    //         16 frags/thread; each frag = 8 strided W loads (L2-hot, 64 KB total)
    //         packed to bf16x8, one ds_write_b128.
    #pragma unroll
    for (int i = 0; i < 16; ++i) {
        int f  = tid + i * 128;          // 0..2047
        int ks = f >> 8;
        int nt = (f >> 6) & 3;
        int fl = f & 63;
        int fq = fl >> 4;
        int c  = nt * 16 + (fl & 15);
        const float* wp = W + (size_t)(ks * 32 + fq * 8) * DDIM + c;
        union { short8 s; unsigned int u[4]; } fr;
        fr.u[0] = pack2_bf16(wp[0 * DDIM], wp[1 * DDIM]);
        fr.u[1] = pack2_bf16(wp[2 * DDIM], wp[3 * DDIM]);
        fr.u[2] = pack2_bf16(wp[4 * DDIM], wp[5 * DDIM]);
        fr.u[3] = pack2_bf16(wp[6 * DDIM], wp[7 * DDIM]);
        reinterpret_cast<short8*>(bfrag_lds)[f] = fr.s;
    }

    // ---- 3) Bias partial colsums: thread (h=tid>>4, c4=tid&15) sums 32 f-rows
    //         of float4 column group c4. 32 coalesced float4 loads/thread.
    {
        const int c4 = tid & 15;
        const int h  = tid >> 4;         // 0..7
        const float4* bp = reinterpret_cast<const float4*>(b) + c4;
        float4 s = make_float4(0.f, 0.f, 0.f, 0.f);
        #pragma unroll 8
        for (int f = h * 32; f < h * 32 + 32; ++f) {
            float4 v = bp[(size_t)f * 16];
            s.x += v.x; s.y += v.y; s.z += v.z; s.w += v.w;
        }
        bias_part[h][c4] = s;
    }

    __syncthreads();

    // ---- 4) MFMA K-loop: pack A-frag from regs, one ds_read_b128 per B-frag.
    floatx4 acc[4] = {{0.f, 0.f, 0.f, 0.f}, {0.f, 0.f, 0.f, 0.f},
                      {0.f, 0.f, 0.f, 0.f}, {0.f, 0.f, 0.f, 0.f}};
    #pragma unroll
    for (int ks = 0; ks < 8; ++ks) {
        union { short8 s; unsigned int u[4]; } fa;
        float4 v0 = xv[2 * ks], v1 = xv[2 * ks + 1];
        fa.u[0] = pack2_bf16(v0.x, v0.y);
        fa.u[1] = pack2_bf16(v0.z, v0.w);
        fa.u[2] = pack2_bf16(v1.x, v1.y);
        fa.u[3] = pack2_bf16(v1.z, v1.w);
        #pragma unroll
        for (int nt = 0; nt < 4; ++nt) {
            short8 fb = reinterpret_cast<const short8*>(bfrag_lds)[ks * 256 + nt * 64 + lane];
            acc[nt] = __builtin_amdgcn_mfma_f32_16x16x32_bf16(fa.s, fb, acc[nt], 0, 0, 0);
        }
    }

    // ---- 5) Epilogue: fold bias (exact fp32 colsum) + 1/256 scale; 16 dword
    //         stores, 64B-coalesced per quad.
    #pragma unroll
    for (int nt = 0; nt < 4; ++nt) {
        const int c = nt * 16 + n;
        float bs = 0.f;
        #pragma unroll
        for (int h = 0; h < 8; ++h)
            bs += reinterpret_cast<const float*>(&bias_part[h][0])[c];  // broadcast reads
        #pragma unroll
        for (int reg = 0; reg < 4; ++reg) {
            const int r = r0 + w * 16 + q * 4 + reg;
            out[(size_t)r * DDIM + c] = (acc[nt][reg] + bs) * (1.0f / 256.0f);
        }
    }
}

extern "C" void kernel_launch(void* const* d_in, const int* in_sizes, int n_in,
                              void* d_out, int out_size, void* d_ws, size_t ws_size,
                              hipStream_t stream) {
    const float* x = (const float*)d_in[0];   // [8192, 256]
    const float* W = (const float*)d_in[1];   // [256, 64]
    const float* b = (const float*)d_in[2];   // [256, 64]
    float* out = (float*)d_out;               // [8192, 64]

    nanembed_mfma<<<dim3(NROWS / 32), 128, 0, stream>>>(x, W, b, out);
}